// Round 1
// baseline (226.164 us; speedup 1.0000x reference)
//
#include <hip/hip_runtime.h>

// Problem constants (from setup_inputs): q,k are (4,4,4096,256) float32; h=w=64 at runtime.
constexpr int B_ = 4, H_ = 4, N_ = 4096, C_ = 256;
constexpr long long TENS = (long long)B_ * H_ * N_ * C_;   // 16,777,216 elements per tensor
constexpr int VEC = 4;                                     // floats per thread per tensor (1 float4)
constexpr long long NTHREADS = TENS / VEC;                 // 4,194,304 threads
constexpr int F4_PER_POS = C_ / 4;                         // 64 float4 table entries per position
constexpr int TAB_ENTRIES = N_ * F4_PER_POS;               // 262,144 float4 entries
constexpr size_t TAB_BYTES = (size_t)TAB_ENTRIES * 16;     // 4 MiB

// native vector type so __builtin_nontemporal_{load,store} accept it
typedef float f32x4 __attribute__((ext_vector_type(4)));

__device__ __forceinline__ unsigned read_w(const int* __restrict__ wp) {
    // Robust read of scalar w: accept int32 (expected) or float32 bit patterns.
    int wi = wp[0];
    if (wi <= 0 || wi > 65536) {
        float wf = __int_as_float(wi);
        wi = (wf > 0.0f && wf <= 65536.0f) ? (int)wf : 64;
    }
    return (unsigned)wi;
}

// ---------------------------------------------------------------------------
// Kernel 1: build the (pos, channel-quad) -> (cos0, sin0, cos1, sin1) table.
// 262,144 entries, 2 sincosf each — runs in a few microseconds, once per launch
// (workspace may be re-poisoned between iterations, so we always rebuild).
// Entry layout matches the flattened tensor index: tab[pos*64 + (t & 63)].
// ---------------------------------------------------------------------------
__global__ __launch_bounds__(256) void build_tab_kernel(
    const int* __restrict__ wp, f32x4* __restrict__ tab)
{
    const unsigned idx = blockIdx.x * 256 + threadIdx.x;    // [0, TAB_ENTRIES)
    const unsigned w = read_w(wp);
    const unsigned pos = idx >> 6;                          // sequence index 0..4095
    const unsigned fq  = idx & 63;                          // float4 index within channel row
    const unsigned x = pos % w;
    const unsigned y = pos / w;
    // channel quad fq covers pairs j0=2*fq, j0+1. j0<64 => x-side, else y-side.
    const float mult = (fq < 32) ? (float)x : (float)y;
    const int f0 = (int)(2u * (fq & 31u));                  // even frequency index in [0,64)
    // base[f] = 10000^(-f/64) = exp2(f * -log2(10000)/64)
    constexpr float NEG_LOG2_THETA_OVER_64 = -0.20762050593045494f;
    float c0, s0, c1, s1;
    sincosf(mult * exp2f((float)f0       * NEG_LOG2_THETA_OVER_64), &s0, &c0);
    sincosf(mult * exp2f((float)(f0 + 1) * NEG_LOG2_THETA_OVER_64), &s1, &c1);
    f32x4 v; v.x = c0; v.y = s0; v.z = c1; v.w = s1;
    tab[idx] = v;
}

// ---------------------------------------------------------------------------
// Kernel 2: pure-streaming RoPE apply. Per thread: 1 cached table load (f32x4),
// 2 nontemporal loads, 8 FMA, 2 nontemporal stores. Zero transcendentals.
// Table index = t & 0x3FFFF since t = bh*2^18 + pos*64 + fq.
// ---------------------------------------------------------------------------
__global__ __launch_bounds__(256) void rope2d_tab_kernel(
    const f32x4* __restrict__ q4,
    const f32x4* __restrict__ k4,
    const f32x4* __restrict__ tab,
    f32x4* __restrict__ oq4,
    f32x4* __restrict__ ok4)
{
    const unsigned t = blockIdx.x * 256 + threadIdx.x;
    const f32x4 cs = tab[t & (unsigned)(TAB_ENTRIES - 1)];  // L2-resident (4 MiB, reused 16x)
    const f32x4 qa = __builtin_nontemporal_load(&q4[t]);
    const f32x4 ka = __builtin_nontemporal_load(&k4[t]);

    f32x4 r;
    r.x = fmaf(cs.x, qa.x, -cs.y * qa.y);
    r.y = fmaf(cs.y, qa.x,  cs.x * qa.y);
    r.z = fmaf(cs.z, qa.z, -cs.w * qa.w);
    r.w = fmaf(cs.w, qa.z,  cs.z * qa.w);
    __builtin_nontemporal_store(r, &oq4[t]);

    r.x = fmaf(cs.x, ka.x, -cs.y * ka.y);
    r.y = fmaf(cs.y, ka.x,  cs.x * ka.y);
    r.z = fmaf(cs.z, ka.z, -cs.w * ka.w);
    r.w = fmaf(cs.w, ka.z,  cs.z * ka.w);
    __builtin_nontemporal_store(r, &ok4[t]);
}

// ---------------------------------------------------------------------------
// Fallback: previous harness-verified inline-trig kernel (used only if the
// workspace is too small for the table).
// ---------------------------------------------------------------------------
__global__ __launch_bounds__(256) void rope2d_inline_kernel(
    const float4* __restrict__ q4,
    const float4* __restrict__ k4,
    const int* __restrict__ wp,
    float4* __restrict__ oq4,
    float4* __restrict__ ok4)
{
    const unsigned w = read_w(wp);
    const unsigned t = blockIdx.x * 256 + threadIdx.x;      // float4 index, lane-contiguous
    const unsigned e = t * VEC;                             // element offset within a tensor

    const int cidx = (int)(e & (C_ - 1));                   // offset within channel row
    const unsigned pos = (e >> 8) & (N_ - 1);               // sequence index n
    const unsigned x = pos % w;
    const unsigned y = pos / w;

    const int j0 = cidx >> 1;                               // first pair index (even, 0..127)
    const float mult = (j0 < C_ / 4) ? (float)x : (float)y;
    const int f0 = j0 & (C_ / 4 - 1);                       // frequency index 0..63

    float cs0, sn0, cs1, sn1;
    sincosf(mult * exp2f((float)(f0    ) * (-0.20762050593045494f)), &sn0, &cs0);
    sincosf(mult * exp2f((float)(f0 + 1) * (-0.20762050593045494f)), &sn1, &cs1);

    const float4 qa = q4[t];
    const float4 ka = k4[t];

    float4 r;
    r.x = fmaf(cs0, qa.x, -sn0 * qa.y);  r.y = fmaf(sn0, qa.x, cs0 * qa.y);
    r.z = fmaf(cs1, qa.z, -sn1 * qa.w);  r.w = fmaf(sn1, qa.z, cs1 * qa.w);
    oq4[t] = r;

    r.x = fmaf(cs0, ka.x, -sn0 * ka.y);  r.y = fmaf(sn0, ka.x, cs0 * ka.y);
    r.z = fmaf(cs1, ka.z, -sn1 * ka.w);  r.w = fmaf(sn1, ka.z, cs1 * ka.w);
    ok4[t] = r;
}

extern "C" void kernel_launch(void* const* d_in, const int* in_sizes, int n_in,
                              void* d_out, int out_size, void* d_ws, size_t ws_size,
                              hipStream_t stream) {
    // dict order: q, k, h, w  (h,w are 1-element arrays on device)
    const int* wp = (const int*)d_in[3];
    float* out = (float*)d_out;                 // q_out flat, then k_out flat

    if (d_ws != nullptr && ws_size >= TAB_BYTES) {
        f32x4* tab = (f32x4*)d_ws;
        build_tab_kernel<<<dim3(TAB_ENTRIES / 256), 256, 0, stream>>>(wp, tab);
        rope2d_tab_kernel<<<dim3((unsigned)(NTHREADS / 256)), 256, 0, stream>>>(
            (const f32x4*)d_in[0], (const f32x4*)d_in[1], tab,
            (f32x4*)out, (f32x4*)(out + TENS));
    } else {
        rope2d_inline_kernel<<<dim3((unsigned)(NTHREADS / 256)), 256, 0, stream>>>(
            (const float4*)d_in[0], (const float4*)d_in[1], wp,
            (float4*)out, (float4*)(out + TENS));
    }
}